// Round 1
// baseline (1375.225 us; speedup 1.0000x reference)
//
#include <hip/hip_runtime.h>
#include <cstdint>
#include <cstddef>

#define CDIV(a,b) (((a)+(b)-1)/(b))

// ---------------- CSR build ----------------

__global__ void k_count(const int* __restrict__ dst, int E, int* __restrict__ cnt) {
  int e = blockIdx.x * blockDim.x + threadIdx.x;
  if (e < E) atomicAdd(&cnt[dst[e]], 1);
}

__global__ void k_scanA(const int* __restrict__ cnt, int n,
                        int* __restrict__ rowp, int* __restrict__ bsum) {
  __shared__ int sh[256];
  int t = threadIdx.x;
  int base = blockIdx.x * 1024 + t * 4;
  int v0 = (base + 0 < n) ? cnt[base + 0] : 0;
  int v1 = (base + 1 < n) ? cnt[base + 1] : 0;
  int v2 = (base + 2 < n) ? cnt[base + 2] : 0;
  int v3 = (base + 3 < n) ? cnt[base + 3] : 0;
  int s = v0 + v1 + v2 + v3;
  sh[t] = s; __syncthreads();
  for (int off = 1; off < 256; off <<= 1) {
    int x = (t >= off) ? sh[t - off] : 0;
    __syncthreads();
    sh[t] += x;
    __syncthreads();
  }
  int run = sh[t] - s;  // exclusive
  if (base + 0 < n) rowp[base + 0] = run; run += v0;
  if (base + 1 < n) rowp[base + 1] = run; run += v1;
  if (base + 2 < n) rowp[base + 2] = run; run += v2;
  if (base + 3 < n) rowp[base + 3] = run;
  if (t == 255) bsum[blockIdx.x] = sh[255];
}

__global__ void k_scanB(int* __restrict__ bsum, int nb) {
  __shared__ int sh[256];
  int t = threadIdx.x;
  int v = (t < nb) ? bsum[t] : 0;
  sh[t] = v; __syncthreads();
  for (int off = 1; off < 256; off <<= 1) {
    int x = (t >= off) ? sh[t - off] : 0;
    __syncthreads();
    sh[t] += x;
    __syncthreads();
  }
  if (t < nb) bsum[t] = sh[t] - v;  // exclusive block offsets
}

__global__ void k_scanC(int* __restrict__ rowp, const int* __restrict__ bsum,
                        int* __restrict__ cnt, float* __restrict__ dinv, int n, int E) {
  int i = blockIdx.x * blockDim.x + threadIdx.x;
  if (i < n) {
    rowp[i] += bsum[i >> 10];
    dinv[i] = rsqrtf((float)(cnt[i] + 1));  // +1 self loop
    cnt[i] = 0;                              // reset for placement pass
    if (i == 0) rowp[n] = E;
  }
}

__global__ void k_place(const int* __restrict__ src, const int* __restrict__ dst, int E,
                        const int* __restrict__ rowp, int* __restrict__ cnt,
                        int* __restrict__ col) {
  int e = blockIdx.x * blockDim.x + threadIdx.x;
  if (e < E) {
    int d = dst[e];
    int p = atomicAdd(&cnt[d], 1);
    col[rowp[d] + p] = src[e];
  }
}

// ---------------- GCN aggregate: out[d] = dinv[d]*(sum_s dinv[s]*x[s] + dinv[d]*x[d]) (+bias) ----

template<int D, bool ADD_BIAS>
__global__ __launch_bounds__(256) void k_aggregate(
    const float* __restrict__ xin, float* __restrict__ xout,
    const int* __restrict__ rowp, const int* __restrict__ col,
    const float* __restrict__ dinv, const float* __restrict__ bias, int n) {
  constexpr int G = D / 4;        // lanes per node
  constexpr int NPB = 256 / G;    // nodes per block
  int node = blockIdx.x * NPB + threadIdx.x / G;
  int g = threadIdx.x % G;
  if (node >= n) return;
  const float4* x4 = (const float4*)xin;
  float di = dinv[node];
  float4 xs = x4[(size_t)node * G + g];
  float ax = di * xs.x, ay = di * xs.y, az = di * xs.z, aw = di * xs.w;  // self loop
  int e1 = rowp[node + 1];
  for (int e = rowp[node]; e < e1; ++e) {
    int s = col[e];
    float w = dinv[s];
    float4 v = x4[(size_t)s * G + g];
    ax += w * v.x; ay += w * v.y; az += w * v.z; aw += w * v.w;
  }
  float4 r;
  r.x = di * ax; r.y = di * ay; r.z = di * az; r.w = di * aw;
  if (ADD_BIAS) {
    float4 b = ((const float4*)bias)[g];
    r.x += b.x; r.y += b.y; r.z += b.z; r.w += b.w;
  }
  ((float4*)xout)[(size_t)node * G + g] = r;
}

// ---------------- GEMM: C[n x dout] = A[n x K] @ W[K x dout] (+bias, relu) ----------------
// 64x64 tile per block, 4x4 per thread, K-chunks of 64 staged in LDS (A transposed, +1 pad).

template<int K, bool RELU>
__global__ __launch_bounds__(256) void k_gemm(
    const float* __restrict__ A, const float* __restrict__ W,
    const float* __restrict__ bias, float* __restrict__ C, int n, int dout) {
  __shared__ float At[64][65];
  __shared__ float Wl[64][64];
  int n0 = blockIdx.x * 64, c0 = blockIdx.y * 64;
  int t = threadIdx.x;
  int tr = t & 15, tc = t >> 4;
  float acc[4][4];
#pragma unroll
  for (int i = 0; i < 4; i++)
#pragma unroll
    for (int j = 0; j < 4; j++) acc[i][j] = 0.f;

  for (int kt = 0; kt < K; kt += 64) {
    if (kt) __syncthreads();
#pragma unroll
    for (int id = t; id < 64 * 64; id += 256) {
      int r = id >> 6, k = id & 63;
      float v = (n0 + r < n) ? A[(size_t)(n0 + r) * K + kt + k] : 0.f;
      At[k][r] = v;
    }
#pragma unroll
    for (int id = t; id < 64 * 64; id += 256) {
      int k = id >> 6, c = id & 63;
      Wl[k][c] = W[(size_t)(kt + k) * dout + c0 + c];
    }
    __syncthreads();
#pragma unroll 8
    for (int k = 0; k < 64; ++k) {
      float a0 = At[k][4 * tr + 0], a1 = At[k][4 * tr + 1];
      float a2 = At[k][4 * tr + 2], a3 = At[k][4 * tr + 3];
      float w0 = Wl[k][4 * tc + 0], w1 = Wl[k][4 * tc + 1];
      float w2 = Wl[k][4 * tc + 2], w3 = Wl[k][4 * tc + 3];
      acc[0][0] += a0 * w0; acc[0][1] += a0 * w1; acc[0][2] += a0 * w2; acc[0][3] += a0 * w3;
      acc[1][0] += a1 * w0; acc[1][1] += a1 * w1; acc[1][2] += a1 * w2; acc[1][3] += a1 * w3;
      acc[2][0] += a2 * w0; acc[2][1] += a2 * w1; acc[2][2] += a2 * w2; acc[2][3] += a2 * w3;
      acc[3][0] += a3 * w0; acc[3][1] += a3 * w1; acc[3][2] += a3 * w2; acc[3][3] += a3 * w3;
    }
  }
  float4 b = make_float4(0.f, 0.f, 0.f, 0.f);
  if (bias) b = ((const float4*)bias)[(c0 >> 2) + tc];
#pragma unroll
  for (int i = 0; i < 4; i++) {
    int row = n0 + 4 * tr + i;
    if (row < n) {
      float4 r;
      r.x = acc[i][0] + b.x; r.y = acc[i][1] + b.y;
      r.z = acc[i][2] + b.z; r.w = acc[i][3] + b.w;
      if (RELU) {
        r.x = fmaxf(r.x, 0.f); r.y = fmaxf(r.y, 0.f);
        r.z = fmaxf(r.z, 0.f); r.w = fmaxf(r.w, 0.f);
      }
      *(float4*)&C[(size_t)row * dout + c0 + 4 * tc] = r;
    }
  }
}

// ---------------- attention pooling ----------------

__global__ void k_colmean(const float* __restrict__ x, int n, double* __restrict__ gcsum) {
  __shared__ double sd[256];
  int t = threadIdx.x;
  int f = t & 63, rg = t >> 6;
  double acc = 0.0;
  for (int r = blockIdx.x * 4 + rg; r < n; r += gridDim.x * 4)
    acc += (double)x[(size_t)r * 64 + f];
  sd[t] = acc; __syncthreads();
  if (t < 64) {
    double tot = sd[t] + sd[t + 64] + sd[t + 128] + sd[t + 192];
    atomicAdd(&gcsum[t], tot);
  }
}

__global__ void k_gc(const double* __restrict__ gcsum, const float* __restrict__ Wa,
                     int n, float* __restrict__ gc) {
  __shared__ float m[64];
  int t = threadIdx.x;  // 64 threads
  m[t] = (float)(gcsum[t] / (double)n);
  __syncthreads();
  float s = 0.f;
  for (int d = 0; d < 64; ++d) s += m[d] * Wa[d * 64 + t];
  gc[t] = tanhf(s);
}

__global__ void k_hsum(const float* __restrict__ x, const float* __restrict__ gc,
                       int n, double* __restrict__ hsum) {
  __shared__ double sd[256][4];
  int t = threadIdx.x;
  int g = t & 15, sub = t >> 4;
  float4 gcv = ((const float4*)gc)[g];
  double a0 = 0, a1 = 0, a2 = 0, a3 = 0;
  for (int node = blockIdx.x * 16 + sub; node < n; node += gridDim.x * 16) {
    float4 xv = ((const float4*)x)[(size_t)node * 16 + g];
    float p = xv.x * gcv.x + xv.y * gcv.y + xv.z * gcv.z + xv.w * gcv.w;
    p += __shfl_xor(p, 1);
    p += __shfl_xor(p, 2);
    p += __shfl_xor(p, 4);
    p += __shfl_xor(p, 8);
    float att = 1.f / (1.f + expf(-p));
    a0 += (double)(att * xv.x); a1 += (double)(att * xv.y);
    a2 += (double)(att * xv.z); a3 += (double)(att * xv.w);
  }
  sd[t][0] = a0; sd[t][1] = a1; sd[t][2] = a2; sd[t][3] = a3;
  __syncthreads();
  if (t < 64) {
    int gg = t >> 2, j = t & 3;
    double tot = 0;
    for (int w = 0; w < 16; ++w) tot += sd[w * 16 + gg][j];
    atomicAdd(&hsum[t], tot);
  }
}

// ---------------- NTN + MLP + score ----------------

__global__ void k_final(const double* __restrict__ hid, const double* __restrict__ hjd,
                        const float* __restrict__ Wt, const float* __restrict__ Wm,
                        const float* __restrict__ bn,
                        const float* __restrict__ w0, const float* __restrict__ b0,
                        const float* __restrict__ w1, const float* __restrict__ b1,
                        const float* __restrict__ w2, const float* __restrict__ b2,
                        const float* __restrict__ w3, const float* __restrict__ b3,
                        const float* __restrict__ sw, const float* __restrict__ sb,
                        float* __restrict__ out) {
  __shared__ float hi[64], hj[64], red[256], z[16];
  int t = threadIdx.x;
  if (t < 64) { hi[t] = (float)hid[t]; hj[t] = (float)hjd[t]; }
  __syncthreads();
  int k = t >> 4, d0 = (t & 15) * 4;
  float p = 0.f;
  for (int d = d0; d < d0 + 4; ++d) {
    const float* wr = Wt + ((size_t)k * 64 + d) * 64;
    float s = 0.f;
    for (int e = 0; e < 64; ++e) s += wr[e] * hj[e];
    p += hi[d] * s;
  }
  red[t] = p; __syncthreads();
  if (t < 16) {
    float bil = 0.f;
    for (int i = 0; i < 16; ++i) bil += red[t * 16 + i];
    float lin = 0.f;
    for (int m = 0; m < 64; ++m) lin += Wm[t * 128 + m] * hi[m];
    for (int m = 0; m < 64; ++m) lin += Wm[t * 128 + 64 + m] * hj[m];
    z[t] = tanhf(bil + lin + bn[t]);
  }
  __syncthreads();
  if (t == 0) {
    float u[32], v[32];
    for (int c = 0; c < 32; ++c) { float s = b0[c]; for (int i = 0; i < 16; ++i) s += z[i] * w0[i * 32 + c]; u[c] = fmaxf(s, 0.f); }
    for (int c = 0; c < 16; ++c) { float s = b1[c]; for (int i = 0; i < 32; ++i) s += u[i] * w1[i * 16 + c]; v[c] = fmaxf(s, 0.f); }
    for (int c = 0; c < 8; ++c)  { float s = b2[c]; for (int i = 0; i < 16; ++i) s += v[i] * w2[i * 8 + c];  u[c] = fmaxf(s, 0.f); }
    for (int c = 0; c < 4; ++c)  { float s = b3[c]; for (int i = 0; i < 8; ++i)  s += u[i] * w3[i * 4 + c];  v[c] = fmaxf(s, 0.f); }
    float s = sb[0];
    for (int i = 0; i < 4; ++i) s += v[i] * sw[i];
    out[0] = s;
  }
}

// ---------------- launch ----------------

extern "C" void kernel_launch(void* const* d_in, const int* in_sizes, int n_in,
                              void* d_out, int out_size, void* d_ws, size_t ws_size,
                              hipStream_t stream) {
  const float* x_i = (const float*)d_in[0];
  const int*   ei  = (const int*)d_in[1];
  const float* x_j = (const float*)d_in[2];
  const int*   ej  = (const int*)d_in[3];
  const float* cw0 = (const float*)d_in[4];  const float* cb0 = (const float*)d_in[5];
  const float* cw1 = (const float*)d_in[6];  const float* cb1 = (const float*)d_in[7];
  const float* cw2 = (const float*)d_in[8];  const float* cb2 = (const float*)d_in[9];
  const float* aw  = (const float*)d_in[10];
  const float* wt  = (const float*)d_in[11]; const float* wm  = (const float*)d_in[12];
  const float* bn  = (const float*)d_in[13];
  const float* m0w = (const float*)d_in[14]; const float* m0b = (const float*)d_in[15];
  const float* m1w = (const float*)d_in[16]; const float* m1b = (const float*)d_in[17];
  const float* m2w = (const float*)d_in[18]; const float* m2b = (const float*)d_in[19];
  const float* m3w = (const float*)d_in[20]; const float* m3b = (const float*)d_in[21];
  const float* sw  = (const float*)d_in[22]; const float* sb  = (const float*)d_in[23];

  int N = in_sizes[0] / 64;
  int E = in_sizes[1] / 2;

  char* p = (char*)d_ws;
  auto alloc = [&](size_t b) -> void* {
    void* r = (void*)p;
    p += (b + 255) & ~(size_t)255;
    return r;
  };
  int*    cnt   = (int*)alloc((size_t)N * 4);
  int*    rowp  = (int*)alloc((size_t)(N + 1) * 4);
  int*    col   = (int*)alloc((size_t)E * 4);
  float*  dinv  = (float*)alloc((size_t)N * 4);
  int*    bsum  = (int*)alloc(4096);
  float*  B0    = (float*)alloc((size_t)N * 128 * 4);
  float*  B1    = (float*)alloc((size_t)N * 128 * 4);
  double* gcsum = (double*)alloc(64 * 8);
  float*  gc    = (float*)alloc(64 * 4);
  double* h0    = (double*)alloc(64 * 8);
  double* h1    = (double*)alloc(64 * 8);

  hipMemsetAsync(h0, 0, 64 * 8, stream);
  hipMemsetAsync(h1, 0, 64 * 8, stream);

  for (int g = 0; g < 2; ++g) {
    const float* X  = g ? x_j : x_i;
    const int* src  = g ? ej : ei;
    const int* dst  = src + E;
    double* hs      = g ? h1 : h0;

    hipMemsetAsync(cnt, 0, (size_t)N * 4, stream);
    k_count<<<CDIV(E, 256), 256, 0, stream>>>(dst, E, cnt);
    int nb = CDIV(N, 1024);
    k_scanA<<<nb, 256, 0, stream>>>(cnt, N, rowp, bsum);
    k_scanB<<<1, 256, 0, stream>>>(bsum, nb);
    k_scanC<<<CDIV(N, 256), 256, 0, stream>>>(rowp, bsum, cnt, dinv, N, E);
    k_place<<<CDIV(E, 256), 256, 0, stream>>>(src, dst, E, rowp, cnt, col);

    // L0: aggregate X (64) -> B0, then B1 = relu(B0 @ W0 + b0)  [N x 128]
    k_aggregate<64, false><<<CDIV(N, 16), 256, 0, stream>>>(X, B0, rowp, col, dinv, nullptr, N);
    k_gemm<64, true><<<dim3(CDIV(N, 64), 2), 256, 0, stream>>>(B0, cw0, cb0, B1, N, 128);
    // L1: aggregate B1 (128) -> B0, then B1 = relu(B0 @ W1 + b1)  [N x 128]
    k_aggregate<128, false><<<CDIV(N, 8), 256, 0, stream>>>(B1, B0, rowp, col, dinv, nullptr, N);
    k_gemm<128, true><<<dim3(CDIV(N, 64), 2), 256, 0, stream>>>(B0, cw1, cb1, B1, N, 128);
    // L2: B0 = B1 @ W2 [N x 64], then B1 = aggregate(B0) + b2  (no relu)
    k_gemm<128, false><<<dim3(CDIV(N, 64), 1), 256, 0, stream>>>(B1, cw2, nullptr, B0, N, 64);
    k_aggregate<64, true><<<CDIV(N, 16), 256, 0, stream>>>(B0, B1, rowp, col, dinv, cb2, N);

    // attention pooling -> hs[64] (double)
    hipMemsetAsync(gcsum, 0, 64 * 8, stream);
    k_colmean<<<512, 256, 0, stream>>>(B1, N, gcsum);
    k_gc<<<1, 64, 0, stream>>>(gcsum, aw, N, gc);
    k_hsum<<<512, 256, 0, stream>>>(B1, gc, N, hs);
  }

  k_final<<<1, 256, 0, stream>>>(h0, h1, wt, wm, bn,
                                 m0w, m0b, m1w, m1b, m2w, m2b, m3w, m3b,
                                 sw, sb, (float*)d_out);
}

// Round 2
// 1069.524 us; speedup vs baseline: 1.2858x; 1.2858x over previous
//
#include <hip/hip_runtime.h>
#include <cstdint>
#include <cstddef>

#define CDIV(a,b) (((a)+(b)-1)/(b))

typedef __attribute__((ext_vector_type(8))) unsigned short ushort8v;

__device__ __forceinline__ float bf2f(unsigned short u) {
  return __uint_as_float(((unsigned)u) << 16);
}
__device__ __forceinline__ unsigned short f2bf(float f) {
  unsigned u = __float_as_uint(f);
  unsigned r = (u + 0x7fff + ((u >> 16) & 1)) >> 16;
  return (unsigned short)r;
}

// ---------------- CSR build ----------------

__global__ void k_count(const int* __restrict__ dst, int E, int* __restrict__ cnt) {
  int e = blockIdx.x * blockDim.x + threadIdx.x;
  if (e < E) atomicAdd(&cnt[dst[e]], 1);
}

__global__ void k_scanA(const int* __restrict__ cnt, int n,
                        int* __restrict__ rowp, int* __restrict__ bsum) {
  __shared__ int sh[256];
  int t = threadIdx.x;
  int base = blockIdx.x * 1024 + t * 4;
  int v0 = (base + 0 < n) ? cnt[base + 0] : 0;
  int v1 = (base + 1 < n) ? cnt[base + 1] : 0;
  int v2 = (base + 2 < n) ? cnt[base + 2] : 0;
  int v3 = (base + 3 < n) ? cnt[base + 3] : 0;
  int s = v0 + v1 + v2 + v3;
  sh[t] = s; __syncthreads();
  for (int off = 1; off < 256; off <<= 1) {
    int x = (t >= off) ? sh[t - off] : 0;
    __syncthreads();
    sh[t] += x;
    __syncthreads();
  }
  int run = sh[t] - s;  // exclusive
  if (base + 0 < n) rowp[base + 0] = run; run += v0;
  if (base + 1 < n) rowp[base + 1] = run; run += v1;
  if (base + 2 < n) rowp[base + 2] = run; run += v2;
  if (base + 3 < n) rowp[base + 3] = run;
  if (t == 255) bsum[blockIdx.x] = sh[255];
}

__global__ void k_scanB(int* __restrict__ bsum, int nb) {
  __shared__ int sh[256];
  int t = threadIdx.x;
  int v = (t < nb) ? bsum[t] : 0;
  sh[t] = v; __syncthreads();
  for (int off = 1; off < 256; off <<= 1) {
    int x = (t >= off) ? sh[t - off] : 0;
    __syncthreads();
    sh[t] += x;
    __syncthreads();
  }
  if (t < nb) bsum[t] = sh[t] - v;
}

__global__ void k_scanC(int* __restrict__ rowp, const int* __restrict__ bsum,
                        int* __restrict__ cnt, float* __restrict__ dinv, int n, int E) {
  int i = blockIdx.x * blockDim.x + threadIdx.x;
  if (i < n) {
    rowp[i] += bsum[i >> 10];
    dinv[i] = rsqrtf((float)(cnt[i] + 1));  // +1 self loop
    cnt[i] = 0;
    if (i == 0) rowp[n] = E;
  }
}

__global__ void k_place(const int* __restrict__ src, const int* __restrict__ dst, int E,
                        const int* __restrict__ rowp, int* __restrict__ cnt,
                        int* __restrict__ col) {
  int e = blockIdx.x * blockDim.x + threadIdx.x;
  if (e < E) {
    int d = dst[e];
    int p = atomicAdd(&cnt[d], 1);
    col[rowp[d] + p] = src[e];
  }
}

// ---------------- f32 -> bf16 convert ----------------

__global__ void k_tobf(const float* __restrict__ in, unsigned short* __restrict__ out, int n8) {
  int i = blockIdx.x * blockDim.x + threadIdx.x;
  if (i < n8) {
    const float4* i4 = (const float4*)in;
    float4 a = i4[2 * i], b = i4[2 * i + 1];
    ushort8v r;
    r[0] = f2bf(a.x); r[1] = f2bf(a.y); r[2] = f2bf(a.z); r[3] = f2bf(a.w);
    r[4] = f2bf(b.x); r[5] = f2bf(b.y); r[6] = f2bf(b.z); r[7] = f2bf(b.w);
    ((ushort8v*)out)[i] = r;
  }
}

// -------- GCN aggregate (bf16 in, f32 out): out[d] = dinv[d]*(sum dinv[s]*x[s] + dinv[d]*x[d]) --------

template<int D, bool ADD_BIAS>
__global__ __launch_bounds__(256) void k_agg(
    const unsigned short* __restrict__ xin, float* __restrict__ xout,
    const int* __restrict__ rowp, const int* __restrict__ col,
    const float* __restrict__ dinv, const float* __restrict__ bias, int n) {
  constexpr int G = D / 8;        // lanes per node, 16B (8 bf16) per lane
  constexpr int NPB = 256 / G;
  int node = blockIdx.x * NPB + threadIdx.x / G;
  int g = threadIdx.x % G;
  if (node >= n) return;
  const ushort8v* x8 = (const ushort8v*)xin;
  float di = dinv[node];
  float acc[8];
  {
    ushort8v xs = x8[(size_t)node * G + g];
#pragma unroll
    for (int j = 0; j < 8; ++j) acc[j] = di * bf2f(xs[j]);  // self loop
  }
  int e = rowp[node], e1 = rowp[node + 1];
  for (; e + 4 <= e1; e += 4) {
    int s0 = col[e], s1 = col[e + 1], s2 = col[e + 2], s3 = col[e + 3];
    float w0 = dinv[s0], w1 = dinv[s1], w2 = dinv[s2], w3 = dinv[s3];
    ushort8v v0 = x8[(size_t)s0 * G + g];
    ushort8v v1 = x8[(size_t)s1 * G + g];
    ushort8v v2 = x8[(size_t)s2 * G + g];
    ushort8v v3 = x8[(size_t)s3 * G + g];
#pragma unroll
    for (int j = 0; j < 8; ++j) {
      acc[j] += w0 * bf2f(v0[j]);
      acc[j] += w1 * bf2f(v1[j]);
      acc[j] += w2 * bf2f(v2[j]);
      acc[j] += w3 * bf2f(v3[j]);
    }
  }
  for (; e < e1; ++e) {
    int s = col[e];
    float w = dinv[s];
    ushort8v v = x8[(size_t)s * G + g];
#pragma unroll
    for (int j = 0; j < 8; ++j) acc[j] += w * bf2f(v[j]);
  }
  float r[8];
#pragma unroll
  for (int j = 0; j < 8; ++j) {
    r[j] = di * acc[j];
    if (ADD_BIAS) r[j] += bias[g * 8 + j];
  }
  float* op = xout + (size_t)node * D + g * 8;
  *(float4*)(op + 0) = make_float4(r[0], r[1], r[2], r[3]);
  *(float4*)(op + 4) = make_float4(r[4], r[5], r[6], r[7]);
}

// ---------------- GEMM: C[n x dout] = A[n x K] @ W[K x dout] (+bias, relu, opt bf16 out) --------

template<int K, bool RELU, bool BF16OUT>
__global__ __launch_bounds__(256) void k_gemm(
    const float* __restrict__ A, const float* __restrict__ W,
    const float* __restrict__ bias, void* __restrict__ Cv, int n, int dout) {
  __shared__ float At[64][65];
  __shared__ float Wl[64][64];
  int n0 = blockIdx.x * 64, c0 = blockIdx.y * 64;
  int t = threadIdx.x;
  int tr = t & 15, tc = t >> 4;
  float acc[4][4];
#pragma unroll
  for (int i = 0; i < 4; i++)
#pragma unroll
    for (int j = 0; j < 4; j++) acc[i][j] = 0.f;

  for (int kt = 0; kt < K; kt += 64) {
    if (kt) __syncthreads();
#pragma unroll
    for (int id = t; id < 64 * 16; id += 256) {
      int r = id >> 4, k4 = id & 15;
      float4 v = make_float4(0.f, 0.f, 0.f, 0.f);
      if (n0 + r < n) v = *(const float4*)&A[(size_t)(n0 + r) * K + kt + 4 * k4];
      At[4 * k4 + 0][r] = v.x; At[4 * k4 + 1][r] = v.y;
      At[4 * k4 + 2][r] = v.z; At[4 * k4 + 3][r] = v.w;
    }
#pragma unroll
    for (int id = t; id < 64 * 16; id += 256) {
      int k = id >> 4, c4 = id & 15;
      *(float4*)&Wl[k][4 * c4] = *(const float4*)&W[(size_t)(kt + k) * dout + c0 + 4 * c4];
    }
    __syncthreads();
#pragma unroll 8
    for (int k = 0; k < 64; ++k) {
      float a0 = At[k][4 * tr + 0], a1 = At[k][4 * tr + 1];
      float a2 = At[k][4 * tr + 2], a3 = At[k][4 * tr + 3];
      float w0 = Wl[k][4 * tc + 0], w1 = Wl[k][4 * tc + 1];
      float w2 = Wl[k][4 * tc + 2], w3 = Wl[k][4 * tc + 3];
      acc[0][0] += a0 * w0; acc[0][1] += a0 * w1; acc[0][2] += a0 * w2; acc[0][3] += a0 * w3;
      acc[1][0] += a1 * w0; acc[1][1] += a1 * w1; acc[1][2] += a1 * w2; acc[1][3] += a1 * w3;
      acc[2][0] += a2 * w0; acc[2][1] += a2 * w1; acc[2][2] += a2 * w2; acc[2][3] += a2 * w3;
      acc[3][0] += a3 * w0; acc[3][1] += a3 * w1; acc[3][2] += a3 * w2; acc[3][3] += a3 * w3;
    }
  }
  float4 b = make_float4(0.f, 0.f, 0.f, 0.f);
  if (bias) b = ((const float4*)bias)[(c0 >> 2) + tc];
#pragma unroll
  for (int i = 0; i < 4; i++) {
    int row = n0 + 4 * tr + i;
    if (row < n) {
      float4 r;
      r.x = acc[i][0] + b.x; r.y = acc[i][1] + b.y;
      r.z = acc[i][2] + b.z; r.w = acc[i][3] + b.w;
      if (RELU) {
        r.x = fmaxf(r.x, 0.f); r.y = fmaxf(r.y, 0.f);
        r.z = fmaxf(r.z, 0.f); r.w = fmaxf(r.w, 0.f);
      }
      if (BF16OUT) {
        ushort4 u;
        u.x = f2bf(r.x); u.y = f2bf(r.y); u.z = f2bf(r.z); u.w = f2bf(r.w);
        *(ushort4*)&((unsigned short*)Cv)[(size_t)row * dout + c0 + 4 * tc] = u;
      } else {
        *(float4*)&((float*)Cv)[(size_t)row * dout + c0 + 4 * tc] = r;
      }
    }
  }
}

// ---------------- attention pooling ----------------

__global__ void k_colmean(const float* __restrict__ x, int n, double* __restrict__ gcsum) {
  __shared__ double sd[256];
  int t = threadIdx.x;
  int f = t & 63, rg = t >> 6;
  double acc = 0.0;
  for (int r = blockIdx.x * 4 + rg; r < n; r += gridDim.x * 4)
    acc += (double)x[(size_t)r * 64 + f];
  sd[t] = acc; __syncthreads();
  if (t < 64) {
    double tot = sd[t] + sd[t + 64] + sd[t + 128] + sd[t + 192];
    atomicAdd(&gcsum[t], tot);
  }
}

__global__ void k_gc(const double* __restrict__ gcsum, const float* __restrict__ Wa,
                     int n, float* __restrict__ gc) {
  __shared__ float m[64];
  int t = threadIdx.x;  // 64 threads
  m[t] = (float)(gcsum[t] / (double)n);
  __syncthreads();
  float s = 0.f;
  for (int d = 0; d < 64; ++d) s += m[d] * Wa[d * 64 + t];
  gc[t] = tanhf(s);
}

__global__ void k_hsum(const float* __restrict__ x, const float* __restrict__ gc,
                       int n, double* __restrict__ hsum) {
  __shared__ double sd[256][4];
  int t = threadIdx.x;
  int g = t & 15, sub = t >> 4;
  float4 gcv = ((const float4*)gc)[g];
  double a0 = 0, a1 = 0, a2 = 0, a3 = 0;
  for (int node = blockIdx.x * 16 + sub; node < n; node += gridDim.x * 16) {
    float4 xv = ((const float4*)x)[(size_t)node * 16 + g];
    float p = xv.x * gcv.x + xv.y * gcv.y + xv.z * gcv.z + xv.w * gcv.w;
    p += __shfl_xor(p, 1);
    p += __shfl_xor(p, 2);
    p += __shfl_xor(p, 4);
    p += __shfl_xor(p, 8);
    float att = 1.f / (1.f + expf(-p));
    a0 += (double)(att * xv.x); a1 += (double)(att * xv.y);
    a2 += (double)(att * xv.z); a3 += (double)(att * xv.w);
  }
  sd[t][0] = a0; sd[t][1] = a1; sd[t][2] = a2; sd[t][3] = a3;
  __syncthreads();
  if (t < 64) {
    int gg = t >> 2, j = t & 3;
    double tot = 0;
    for (int w = 0; w < 16; ++w) tot += sd[w * 16 + gg][j];
    atomicAdd(&hsum[t], tot);
  }
}

// ---------------- NTN + MLP + score ----------------

__global__ void k_final(const double* __restrict__ hid, const double* __restrict__ hjd,
                        const float* __restrict__ Wt, const float* __restrict__ Wm,
                        const float* __restrict__ bn,
                        const float* __restrict__ w0, const float* __restrict__ b0,
                        const float* __restrict__ w1, const float* __restrict__ b1,
                        const float* __restrict__ w2, const float* __restrict__ b2,
                        const float* __restrict__ w3, const float* __restrict__ b3,
                        const float* __restrict__ sw, const float* __restrict__ sb,
                        float* __restrict__ out) {
  __shared__ float hi[64], hj[64], red[256], z[16];
  int t = threadIdx.x;
  if (t < 64) { hi[t] = (float)hid[t]; hj[t] = (float)hjd[t]; }
  __syncthreads();
  int k = t >> 4, d0 = (t & 15) * 4;
  float p = 0.f;
  for (int d = d0; d < d0 + 4; ++d) {
    const float* wr = Wt + ((size_t)k * 64 + d) * 64;
    float s = 0.f;
    for (int e = 0; e < 64; ++e) s += wr[e] * hj[e];
    p += hi[d] * s;
  }
  red[t] = p; __syncthreads();
  if (t < 16) {
    float bil = 0.f;
    for (int i = 0; i < 16; ++i) bil += red[t * 16 + i];
    float lin = 0.f;
    for (int m = 0; m < 64; ++m) lin += Wm[t * 128 + m] * hi[m];
    for (int m = 0; m < 64; ++m) lin += Wm[t * 128 + 64 + m] * hj[m];
    z[t] = tanhf(bil + lin + bn[t]);
  }
  __syncthreads();
  if (t == 0) {
    float u[32], v[32];
    for (int c = 0; c < 32; ++c) { float s = b0[c]; for (int i = 0; i < 16; ++i) s += z[i] * w0[i * 32 + c]; u[c] = fmaxf(s, 0.f); }
    for (int c = 0; c < 16; ++c) { float s = b1[c]; for (int i = 0; i < 32; ++i) s += u[i] * w1[i * 16 + c]; v[c] = fmaxf(s, 0.f); }
    for (int c = 0; c < 8; ++c)  { float s = b2[c]; for (int i = 0; i < 16; ++i) s += v[i] * w2[i * 8 + c];  u[c] = fmaxf(s, 0.f); }
    for (int c = 0; c < 4; ++c)  { float s = b3[c]; for (int i = 0; i < 8; ++i)  s += u[i] * w3[i * 4 + c];  v[c] = fmaxf(s, 0.f); }
    float s = sb[0];
    for (int i = 0; i < 4; ++i) s += v[i] * sw[i];
    out[0] = s;
  }
}

// ---------------- launch ----------------

extern "C" void kernel_launch(void* const* d_in, const int* in_sizes, int n_in,
                              void* d_out, int out_size, void* d_ws, size_t ws_size,
                              hipStream_t stream) {
  const float* x_i = (const float*)d_in[0];
  const int*   ei  = (const int*)d_in[1];
  const float* x_j = (const float*)d_in[2];
  const int*   ej  = (const int*)d_in[3];
  const float* cw0 = (const float*)d_in[4];  const float* cb0 = (const float*)d_in[5];
  const float* cw1 = (const float*)d_in[6];  const float* cb1 = (const float*)d_in[7];
  const float* cw2 = (const float*)d_in[8];  const float* cb2 = (const float*)d_in[9];
  const float* aw  = (const float*)d_in[10];
  const float* wt  = (const float*)d_in[11]; const float* wm  = (const float*)d_in[12];
  const float* bn  = (const float*)d_in[13];
  const float* m0w = (const float*)d_in[14]; const float* m0b = (const float*)d_in[15];
  const float* m1w = (const float*)d_in[16]; const float* m1b = (const float*)d_in[17];
  const float* m2w = (const float*)d_in[18]; const float* m2b = (const float*)d_in[19];
  const float* m3w = (const float*)d_in[20]; const float* m3b = (const float*)d_in[21];
  const float* sw  = (const float*)d_in[22]; const float* sb  = (const float*)d_in[23];

  int N = in_sizes[0] / 64;
  int E = in_sizes[1] / 2;

  char* p = (char*)d_ws;
  auto alloc = [&](size_t b) -> void* {
    void* r = (void*)p;
    p += (b + 255) & ~(size_t)255;
    return r;
  };
  int*    cnt   = (int*)alloc((size_t)N * 4);
  int*    rowp  = (int*)alloc((size_t)(N + 1) * 4);
  int*    col   = (int*)alloc((size_t)E * 4);
  float*  dinv  = (float*)alloc((size_t)N * 4);
  int*    bsum  = (int*)alloc(4096);
  double* gcsum = (double*)alloc(64 * 8);
  double* hsum  = (double*)alloc(128 * 8);   // h0 | h1
  float*  gc    = (float*)alloc(64 * 4);
  float*  S1    = (float*)alloc((size_t)N * 128 * 4);   // 51.2 MB slot
  float*  S2    = (float*)alloc((size_t)N * 128 * 4);   // 51.2 MB slot

  hipMemsetAsync(hsum, 0, 128 * 8, stream);

  for (int g = 0; g < 2; ++g) {
    const float* X  = g ? x_j : x_i;
    const int* src  = g ? ej : ei;
    const int* dst  = src + E;
    double* hs      = hsum + g * 64;

    // CSR
    hipMemsetAsync(cnt, 0, (size_t)N * 4, stream);
    k_count<<<CDIV(E, 256), 256, 0, stream>>>(dst, E, cnt);
    int nb = CDIV(N, 1024);
    k_scanA<<<nb, 256, 0, stream>>>(cnt, N, rowp, bsum);
    k_scanB<<<1, 256, 0, stream>>>(bsum, nb);
    k_scanC<<<CDIV(N, 256), 256, 0, stream>>>(rowp, bsum, cnt, dinv, N, E);
    k_place<<<CDIV(E, 256), 256, 0, stream>>>(src, dst, E, rowp, cnt, col);

    // xbf = bf16(X) in S2
    unsigned short* xbf = (unsigned short*)S2;
    k_tobf<<<CDIV(N * 8, 256), 256, 0, stream>>>(X, xbf, N * 8);

    // L0: A0(f32,S1) = agg(xbf);  G0(bf16,S2) = relu(A0@W0+b0)
    k_agg<64, false><<<CDIV(N, 32), 256, 0, stream>>>(xbf, S1, rowp, col, dinv, nullptr, N);
    k_gemm<64, true, true><<<dim3(CDIV(N, 64), 2), 256, 0, stream>>>(S1, cw0, cb0, S2, N, 128);
    // L1: A1(f32,S1) = agg(G0);  G1(f32,S2) = relu(A1@W1+b1)
    k_agg<128, false><<<CDIV(N, 16), 256, 0, stream>>>((unsigned short*)S2, S1, rowp, col, dinv, nullptr, N);
    k_gemm<128, true, false><<<dim3(CDIV(N, 64), 2), 256, 0, stream>>>(S1, cw1, cb1, S2, N, 128);
    // L2: G2(bf16,S1) = G1@W2;  F(f32,S2) = agg(G2) + b2
    k_gemm<128, false, true><<<dim3(CDIV(N, 64), 1), 256, 0, stream>>>(S2, cw2, nullptr, S1, N, 64);
    k_agg<64, true><<<CDIV(N, 32), 256, 0, stream>>>((unsigned short*)S1, S2, rowp, col, dinv, cb2, N);

    // attention pooling on F(S2) -> hs[64] (double)
    hipMemsetAsync(gcsum, 0, 64 * 8, stream);
    k_colmean<<<512, 256, 0, stream>>>(S2, N, gcsum);
    k_gc<<<1, 64, 0, stream>>>(gcsum, aw, N, gc);
    k_hsum<<<512, 256, 0, stream>>>(S2, gc, N, hs);
  }

  k_final<<<1, 256, 0, stream>>>(hsum, hsum + 64, wt, wm, bn,
                                 m0w, m0b, m1w, m1b, m2w, m2b, m3w, m3b,
                                 sw, sb, (float*)d_out);
}

// Round 3
// 858.541 us; speedup vs baseline: 1.6018x; 1.2457x over previous
//
#include <hip/hip_runtime.h>
#include <cstdint>
#include <cstddef>

#define CDIV(a,b) (((a)+(b)-1)/(b))

typedef __attribute__((ext_vector_type(8))) unsigned short ushort8v;

__device__ __forceinline__ float bf2f(unsigned short u) {
  return __uint_as_float(((unsigned)u) << 16);
}
__device__ __forceinline__ unsigned short f2bf(float f) {
  unsigned u = __float_as_uint(f);
  unsigned r = (u + 0x7fff + ((u >> 16) & 1)) >> 16;
  return (unsigned short)r;
}

// ---------------- bucketed CSR build ----------------
// Buckets of 512 node-ids (dst >> 9), 256 buckets cover N=100k.

__global__ __launch_bounds__(256) void k_bcount(const int* __restrict__ dst, int E,
                                                int* __restrict__ bucketCnt) {
  __shared__ int h[256];
  int t = threadIdx.x;
  h[t] = 0;
  __syncthreads();
  int e0 = blockIdx.x * 2048, e1 = min(e0 + 2048, E);
  for (int e = e0 + t; e < e1; e += 256) atomicAdd(&h[dst[e] >> 9], 1);
  __syncthreads();
  if (h[t]) atomicAdd(&bucketCnt[t], h[t]);
}

__global__ void k_bscan(const int* __restrict__ bucketCnt, int* __restrict__ bstart,
                        int* __restrict__ gcur, int* __restrict__ rowp, int n, int E) {
  __shared__ int sh[256];
  int t = threadIdx.x;
  int v = bucketCnt[t];
  sh[t] = v; __syncthreads();
  for (int o = 1; o < 256; o <<= 1) {
    int x = (t >= o) ? sh[t - o] : 0;
    __syncthreads();
    sh[t] += x;
    __syncthreads();
  }
  int ex = sh[t] - v;
  bstart[t] = ex;
  gcur[t] = ex;
  if (t == 255) { bstart[256] = E; rowp[n] = E; }
}

__global__ __launch_bounds__(256) void k_part(const int* __restrict__ src,
                                              const int* __restrict__ dst, int E,
                                              int* __restrict__ gcur, int2* __restrict__ part) {
  __shared__ int bcnt[256], bbase[256], bcur[256];
  int t = threadIdx.x;
  int e0 = blockIdx.x * 4096, e1 = min(e0 + 4096, E);
  bcnt[t] = 0;
  __syncthreads();
  for (int e = e0 + t; e < e1; e += 256) atomicAdd(&bcnt[dst[e] >> 9], 1);
  __syncthreads();
  bbase[t] = bcnt[t] ? atomicAdd(&gcur[t], bcnt[t]) : 0;
  bcur[t] = 0;
  __syncthreads();
  for (int e = e0 + t; e < e1; e += 256) {
    int d = dst[e], s = src[e];
    int b = d >> 9;
    int off = atomicAdd(&bcur[b], 1);
    part[bbase[b] + off] = make_int2(s, d);
  }
}

__global__ __launch_bounds__(256) void k_build(const int2* __restrict__ part,
                                               const int* __restrict__ bstart,
                                               int* __restrict__ rowp, int* __restrict__ col,
                                               float* __restrict__ dinv, int n) {
  __shared__ int cnt[512], off[512], tmp[256];
  int b = blockIdx.x;
  int lo = b << 9;
  if (lo >= n) return;
  int t = threadIdx.x;
  int s0 = bstart[b], s1 = bstart[b + 1];
  cnt[t] = 0; cnt[t + 256] = 0;
  __syncthreads();
  for (int e = s0 + t; e < s1; e += 256) atomicAdd(&cnt[part[e].y - lo], 1);
  __syncthreads();
  int a0 = cnt[2 * t], a1 = cnt[2 * t + 1];
  int ps = a0 + a1;
  tmp[t] = ps; __syncthreads();
  for (int o = 1; o < 256; o <<= 1) {
    int x = (t >= o) ? tmp[t - o] : 0;
    __syncthreads();
    tmp[t] += x;
    __syncthreads();
  }
  int ex = tmp[t] - ps;
  off[2 * t] = ex;
  off[2 * t + 1] = ex + a0;
  __syncthreads();
  for (int i = t; i < 512; i += 256) {
    int node = lo + i;
    if (node < n) {
      rowp[node] = s0 + off[i];
      dinv[node] = rsqrtf((float)(cnt[i] + 1));  // +1 self loop
    }
  }
  __syncthreads();
  for (int e = s0 + t; e < s1; e += 256) {
    int2 pr = part[e];
    int p = atomicAdd(&off[pr.y - lo], 1);
    col[s0 + p] = pr.x;  // confined to [s0,s1): L2-local, full-line writeback
  }
}

// ---------------- f32 -> bf16 convert ----------------

__global__ void k_tobf(const float* __restrict__ in, unsigned short* __restrict__ out, int n8) {
  int i = blockIdx.x * blockDim.x + threadIdx.x;
  if (i < n8) {
    const float4* i4 = (const float4*)in;
    float4 a = i4[2 * i], b = i4[2 * i + 1];
    ushort8v r;
    r[0] = f2bf(a.x); r[1] = f2bf(a.y); r[2] = f2bf(a.z); r[3] = f2bf(a.w);
    r[4] = f2bf(b.x); r[5] = f2bf(b.y); r[6] = f2bf(b.z); r[7] = f2bf(b.w);
    ((ushort8v*)out)[i] = r;
  }
}

// -------- GCN aggregate (bf16 in, f32 out): out[d] = dinv[d]*(sum dinv[s]*x[s] + dinv[d]*x[d]) --------

template<int D, bool ADD_BIAS>
__global__ __launch_bounds__(256) void k_agg(
    const unsigned short* __restrict__ xin, float* __restrict__ xout,
    const int* __restrict__ rowp, const int* __restrict__ col,
    const float* __restrict__ dinv, const float* __restrict__ bias, int n) {
  constexpr int G = D / 8;
  constexpr int NPB = 256 / G;
  int node = blockIdx.x * NPB + threadIdx.x / G;
  int g = threadIdx.x % G;
  if (node >= n) return;
  const ushort8v* x8 = (const ushort8v*)xin;
  float di = dinv[node];
  float acc[8];
  {
    ushort8v xs = x8[(size_t)node * G + g];
#pragma unroll
    for (int j = 0; j < 8; ++j) acc[j] = di * bf2f(xs[j]);
  }
  int e = rowp[node], e1 = rowp[node + 1];
  for (; e + 4 <= e1; e += 4) {
    int s0 = col[e], s1 = col[e + 1], s2 = col[e + 2], s3 = col[e + 3];
    float w0 = dinv[s0], w1 = dinv[s1], w2 = dinv[s2], w3 = dinv[s3];
    ushort8v v0 = x8[(size_t)s0 * G + g];
    ushort8v v1 = x8[(size_t)s1 * G + g];
    ushort8v v2 = x8[(size_t)s2 * G + g];
    ushort8v v3 = x8[(size_t)s3 * G + g];
#pragma unroll
    for (int j = 0; j < 8; ++j) {
      acc[j] += w0 * bf2f(v0[j]);
      acc[j] += w1 * bf2f(v1[j]);
      acc[j] += w2 * bf2f(v2[j]);
      acc[j] += w3 * bf2f(v3[j]);
    }
  }
  for (; e < e1; ++e) {
    int s = col[e];
    float w = dinv[s];
    ushort8v v = x8[(size_t)s * G + g];
#pragma unroll
    for (int j = 0; j < 8; ++j) acc[j] += w * bf2f(v[j]);
  }
  float r[8];
#pragma unroll
  for (int j = 0; j < 8; ++j) {
    r[j] = di * acc[j];
    if (ADD_BIAS) r[j] += bias[g * 8 + j];
  }
  float* op = xout + (size_t)node * D + g * 8;
  *(float4*)(op + 0) = make_float4(r[0], r[1], r[2], r[3]);
  *(float4*)(op + 4) = make_float4(r[4], r[5], r[6], r[7]);
}

// ---------------- GEMM ----------------

template<int K, bool RELU, bool BF16OUT>
__global__ __launch_bounds__(256) void k_gemm(
    const float* __restrict__ A, const float* __restrict__ W,
    const float* __restrict__ bias, void* __restrict__ Cv, int n, int dout) {
  __shared__ float At[64][65];
  __shared__ float Wl[64][64];
  int n0 = blockIdx.x * 64, c0 = blockIdx.y * 64;
  int t = threadIdx.x;
  int tr = t & 15, tc = t >> 4;
  float acc[4][4];
#pragma unroll
  for (int i = 0; i < 4; i++)
#pragma unroll
    for (int j = 0; j < 4; j++) acc[i][j] = 0.f;

  for (int kt = 0; kt < K; kt += 64) {
    if (kt) __syncthreads();
#pragma unroll
    for (int id = t; id < 64 * 16; id += 256) {
      int r = id >> 4, k4 = id & 15;
      float4 v = make_float4(0.f, 0.f, 0.f, 0.f);
      if (n0 + r < n) v = *(const float4*)&A[(size_t)(n0 + r) * K + kt + 4 * k4];
      At[4 * k4 + 0][r] = v.x; At[4 * k4 + 1][r] = v.y;
      At[4 * k4 + 2][r] = v.z; At[4 * k4 + 3][r] = v.w;
    }
#pragma unroll
    for (int id = t; id < 64 * 16; id += 256) {
      int k = id >> 4, c4 = id & 15;
      *(float4*)&Wl[k][4 * c4] = *(const float4*)&W[(size_t)(kt + k) * dout + c0 + 4 * c4];
    }
    __syncthreads();
#pragma unroll 8
    for (int k = 0; k < 64; ++k) {
      float a0 = At[k][4 * tr + 0], a1 = At[k][4 * tr + 1];
      float a2 = At[k][4 * tr + 2], a3 = At[k][4 * tr + 3];
      float w0 = Wl[k][4 * tc + 0], w1 = Wl[k][4 * tc + 1];
      float w2 = Wl[k][4 * tc + 2], w3 = Wl[k][4 * tc + 3];
      acc[0][0] += a0 * w0; acc[0][1] += a0 * w1; acc[0][2] += a0 * w2; acc[0][3] += a0 * w3;
      acc[1][0] += a1 * w0; acc[1][1] += a1 * w1; acc[1][2] += a1 * w2; acc[1][3] += a1 * w3;
      acc[2][0] += a2 * w0; acc[2][1] += a2 * w1; acc[2][2] += a2 * w2; acc[2][3] += a2 * w3;
      acc[3][0] += a3 * w0; acc[3][1] += a3 * w1; acc[3][2] += a3 * w2; acc[3][3] += a3 * w3;
    }
  }
  float4 b = make_float4(0.f, 0.f, 0.f, 0.f);
  if (bias) b = ((const float4*)bias)[(c0 >> 2) + tc];
#pragma unroll
  for (int i = 0; i < 4; i++) {
    int row = n0 + 4 * tr + i;
    if (row < n) {
      float4 r;
      r.x = acc[i][0] + b.x; r.y = acc[i][1] + b.y;
      r.z = acc[i][2] + b.z; r.w = acc[i][3] + b.w;
      if (RELU) {
        r.x = fmaxf(r.x, 0.f); r.y = fmaxf(r.y, 0.f);
        r.z = fmaxf(r.z, 0.f); r.w = fmaxf(r.w, 0.f);
      }
      if (BF16OUT) {
        ushort4 u;
        u.x = f2bf(r.x); u.y = f2bf(r.y); u.z = f2bf(r.z); u.w = f2bf(r.w);
        *(ushort4*)&((unsigned short*)Cv)[(size_t)row * dout + c0 + 4 * tc] = u;
      } else {
        *(float4*)&((float*)Cv)[(size_t)row * dout + c0 + 4 * tc] = r;
      }
    }
  }
}

// ---------------- attention pooling ----------------

__global__ void k_colmean(const float* __restrict__ x, int n, double* __restrict__ gcsum) {
  __shared__ double sd[256];
  int t = threadIdx.x;
  int f = t & 63, rg = t >> 6;
  double acc = 0.0;
  for (int r = blockIdx.x * 4 + rg; r < n; r += gridDim.x * 4)
    acc += (double)x[(size_t)r * 64 + f];
  sd[t] = acc; __syncthreads();
  if (t < 64) {
    double tot = sd[t] + sd[t + 64] + sd[t + 128] + sd[t + 192];
    atomicAdd(&gcsum[t], tot);
  }
}

__global__ void k_gc(const double* __restrict__ gcsum, const float* __restrict__ Wa,
                     int n, float* __restrict__ gc) {
  __shared__ float m[64];
  int t = threadIdx.x;  // 64 threads
  m[t] = (float)(gcsum[t] / (double)n);
  __syncthreads();
  float s = 0.f;
  for (int d = 0; d < 64; ++d) s += m[d] * Wa[d * 64 + t];
  gc[t] = tanhf(s);
}

__global__ void k_hsum(const float* __restrict__ x, const float* __restrict__ gc,
                       int n, double* __restrict__ hsum) {
  __shared__ double sd[256][4];
  int t = threadIdx.x;
  int g = t & 15, sub = t >> 4;
  float4 gcv = ((const float4*)gc)[g];
  double a0 = 0, a1 = 0, a2 = 0, a3 = 0;
  for (int node = blockIdx.x * 16 + sub; node < n; node += gridDim.x * 16) {
    float4 xv = ((const float4*)x)[(size_t)node * 16 + g];
    float p = xv.x * gcv.x + xv.y * gcv.y + xv.z * gcv.z + xv.w * gcv.w;
    p += __shfl_xor(p, 1);
    p += __shfl_xor(p, 2);
    p += __shfl_xor(p, 4);
    p += __shfl_xor(p, 8);
    float att = 1.f / (1.f + expf(-p));
    a0 += (double)(att * xv.x); a1 += (double)(att * xv.y);
    a2 += (double)(att * xv.z); a3 += (double)(att * xv.w);
  }
  sd[t][0] = a0; sd[t][1] = a1; sd[t][2] = a2; sd[t][3] = a3;
  __syncthreads();
  if (t < 64) {
    int gg = t >> 2, j = t & 3;
    double tot = 0;
    for (int w = 0; w < 16; ++w) tot += sd[w * 16 + gg][j];
    atomicAdd(&hsum[t], tot);
  }
}

// ---------------- NTN (16 blocks, one per slice) ----------------

__global__ __launch_bounds__(256) void k_ntn(
    const double* __restrict__ hid, const double* __restrict__ hjd,
    const float* __restrict__ Wt, const float* __restrict__ Wm,
    const float* __restrict__ bn, float* __restrict__ z) {
  __shared__ float hi[64], hj[64], red[256];
  int b = blockIdx.x, t = threadIdx.x;
  if (t < 64) hi[t] = (float)hid[t];
  else if (t < 128) hj[t - 64] = (float)hjd[t - 64];
  __syncthreads();
  int r = t >> 2, c0 = (t & 3) * 16;
  const float* wr = Wt + ((size_t)b * 64 + r) * 64 + c0;
  float p = 0.f;
#pragma unroll
  for (int c = 0; c < 16; ++c) p += wr[c] * hj[c0 + c];
  p *= hi[r];
  if (t < 128) p += Wm[b * 128 + t] * (t < 64 ? hi[t] : hj[t - 64]);
  red[t] = p; __syncthreads();
  for (int o = 128; o > 0; o >>= 1) {
    if (t < o) red[t] += red[t + o];
    __syncthreads();
  }
  if (t == 0) z[b] = tanhf(red[0] + bn[b]);
}

// ---------------- MLP + score (1 block, 64 threads) ----------------

__global__ void k_mlp(const float* __restrict__ z16,
                      const float* __restrict__ w0, const float* __restrict__ b0,
                      const float* __restrict__ w1, const float* __restrict__ b1,
                      const float* __restrict__ w2, const float* __restrict__ b2,
                      const float* __restrict__ w3, const float* __restrict__ b3,
                      const float* __restrict__ sw, const float* __restrict__ sb,
                      float* __restrict__ out) {
  __shared__ float z[16], u[32], v[16], w[8], q[4];
  int t = threadIdx.x;
  if (t < 16) z[t] = z16[t];
  __syncthreads();
  if (t < 32) {
    float s = b0[t];
    for (int i = 0; i < 16; ++i) s += z[i] * w0[i * 32 + t];
    u[t] = fmaxf(s, 0.f);
  }
  __syncthreads();
  if (t < 16) {
    float s = b1[t];
    for (int i = 0; i < 32; ++i) s += u[i] * w1[i * 16 + t];
    v[t] = fmaxf(s, 0.f);
  }
  __syncthreads();
  if (t < 8) {
    float s = b2[t];
    for (int i = 0; i < 16; ++i) s += v[i] * w2[i * 8 + t];
    w[t] = fmaxf(s, 0.f);
  }
  __syncthreads();
  if (t < 4) {
    float s = b3[t];
    for (int i = 0; i < 8; ++i) s += w[i] * w3[i * 4 + t];
    q[t] = fmaxf(s, 0.f);
  }
  __syncthreads();
  if (t == 0) {
    float s = sb[0];
    for (int i = 0; i < 4; ++i) s += q[i] * sw[i];
    out[0] = s;
  }
}

// ---------------- launch ----------------

extern "C" void kernel_launch(void* const* d_in, const int* in_sizes, int n_in,
                              void* d_out, int out_size, void* d_ws, size_t ws_size,
                              hipStream_t stream) {
  const float* x_i = (const float*)d_in[0];
  const int*   ei  = (const int*)d_in[1];
  const float* x_j = (const float*)d_in[2];
  const int*   ej  = (const int*)d_in[3];
  const float* cw0 = (const float*)d_in[4];  const float* cb0 = (const float*)d_in[5];
  const float* cw1 = (const float*)d_in[6];  const float* cb1 = (const float*)d_in[7];
  const float* cw2 = (const float*)d_in[8];  const float* cb2 = (const float*)d_in[9];
  const float* aw  = (const float*)d_in[10];
  const float* wt  = (const float*)d_in[11]; const float* wm  = (const float*)d_in[12];
  const float* bn  = (const float*)d_in[13];
  const float* m0w = (const float*)d_in[14]; const float* m0b = (const float*)d_in[15];
  const float* m1w = (const float*)d_in[16]; const float* m1b = (const float*)d_in[17];
  const float* m2w = (const float*)d_in[18]; const float* m2b = (const float*)d_in[19];
  const float* m3w = (const float*)d_in[20]; const float* m3b = (const float*)d_in[21];
  const float* sw  = (const float*)d_in[22]; const float* sb  = (const float*)d_in[23];

  int N = in_sizes[0] / 64;
  int E = in_sizes[1] / 2;

  char* p = (char*)d_ws;
  auto alloc = [&](size_t b) -> void* {
    void* r = (void*)p;
    p += (b + 255) & ~(size_t)255;
    return r;
  };
  int*    rowp  = (int*)alloc((size_t)(N + 1) * 4);
  int*    col   = (int*)alloc((size_t)E * 4);
  float*  dinv  = (float*)alloc((size_t)N * 4);
  int*    bucketCnt = (int*)alloc(256 * 4);
  int*    bstart    = (int*)alloc(257 * 4);
  int*    gcur      = (int*)alloc(256 * 4);
  double* gcsum = (double*)alloc(64 * 8);
  double* hsum  = (double*)alloc(128 * 8);
  float*  gc    = (float*)alloc(64 * 4);
  float*  zbuf  = (float*)alloc(16 * 4);
  float*  S1    = (float*)alloc((size_t)N * 128 * 4);
  float*  S2    = (float*)alloc((size_t)N * 128 * 4);

  hipMemsetAsync(hsum, 0, 128 * 8, stream);

  for (int g = 0; g < 2; ++g) {
    const float* X  = g ? x_j : x_i;
    const int* src  = g ? ej : ei;
    const int* dst  = src + E;
    double* hs      = hsum + g * 64;

    // ---- CSR (bucketed, write-coalesced) ----
    int2* part = (int2*)S1;  // transient: consumed before S1's first real use
    hipMemsetAsync(bucketCnt, 0, 256 * 4, stream);
    k_bcount<<<CDIV(E, 2048), 256, 0, stream>>>(dst, E, bucketCnt);
    k_bscan<<<1, 256, 0, stream>>>(bucketCnt, bstart, gcur, rowp, N, E);
    k_part<<<CDIV(E, 4096), 256, 0, stream>>>(src, dst, E, gcur, part);
    k_build<<<256, 256, 0, stream>>>(part, bstart, rowp, col, dinv, N);

    // xbf = bf16(X) in S2
    unsigned short* xbf = (unsigned short*)S2;
    k_tobf<<<CDIV(N * 8, 256), 256, 0, stream>>>(X, xbf, N * 8);

    // L0: A0(f32,S1) = agg(xbf);  G0(bf16,S2) = relu(A0@W0+b0)
    k_agg<64, false><<<CDIV(N, 32), 256, 0, stream>>>(xbf, S1, rowp, col, dinv, nullptr, N);
    k_gemm<64, true, true><<<dim3(CDIV(N, 64), 2), 256, 0, stream>>>(S1, cw0, cb0, S2, N, 128);
    // L1: A1(f32,S1) = agg(G0);  G1(f32,S2) = relu(A1@W1+b1)
    k_agg<128, false><<<CDIV(N, 16), 256, 0, stream>>>((unsigned short*)S2, S1, rowp, col, dinv, nullptr, N);
    k_gemm<128, true, false><<<dim3(CDIV(N, 64), 2), 256, 0, stream>>>(S1, cw1, cb1, S2, N, 128);
    // L2: G2(bf16,S1) = G1@W2;  F(f32,S2) = agg(G2) + b2
    k_gemm<128, false, true><<<dim3(CDIV(N, 64), 1), 256, 0, stream>>>(S2, cw2, nullptr, S1, N, 64);
    k_agg<64, true><<<CDIV(N, 32), 256, 0, stream>>>((unsigned short*)S1, S2, rowp, col, dinv, cb2, N);

    // attention pooling on F(S2) -> hs[64] (double)
    hipMemsetAsync(gcsum, 0, 64 * 8, stream);
    k_colmean<<<512, 256, 0, stream>>>(S2, N, gcsum);
    k_gc<<<1, 64, 0, stream>>>(gcsum, aw, N, gc);
    k_hsum<<<512, 256, 0, stream>>>(S2, gc, N, hs);
  }

  k_ntn<<<16, 256, 0, stream>>>(hsum, hsum + 64, wt, wm, bn, zbuf);
  k_mlp<<<1, 64, 0, stream>>>(zbuf, m0w, m0b, m1w, m1b, m2w, m2b, m3w, m3b,
                              sw, sb, (float*)d_out);
}

// Round 4
// 704.645 us; speedup vs baseline: 1.9517x; 1.2184x over previous
//
#include <hip/hip_runtime.h>
#include <cstdint>
#include <cstddef>

#define CDIV(a,b) (((a)+(b)-1)/(b))

typedef __attribute__((ext_vector_type(8))) unsigned short ushort8v;
typedef __attribute__((ext_vector_type(8))) short short8v;
typedef __attribute__((ext_vector_type(4))) float f32x4;

__device__ __forceinline__ float bf2f(unsigned short u) {
  return __uint_as_float(((unsigned)u) << 16);
}
__device__ __forceinline__ unsigned short f2bf(float f) {
  unsigned u = __float_as_uint(f);
  unsigned r = (u + 0x7fff + ((u >> 16) & 1)) >> 16;
  return (unsigned short)r;
}

// ---------------- bucketed CSR build ----------------

__global__ __launch_bounds__(256) void k_bcount(const int* __restrict__ dst, int E,
                                                int* __restrict__ bucketCnt) {
  __shared__ int h[256];
  int t = threadIdx.x;
  h[t] = 0;
  __syncthreads();
  int e0 = blockIdx.x * 2048, e1 = min(e0 + 2048, E);
  for (int e = e0 + t; e < e1; e += 256) atomicAdd(&h[dst[e] >> 9], 1);
  __syncthreads();
  if (h[t]) atomicAdd(&bucketCnt[t], h[t]);
}

__global__ void k_bscan(const int* __restrict__ bucketCnt, int* __restrict__ bstart,
                        int* __restrict__ gcur, int* __restrict__ rowp, int n, int E) {
  __shared__ int sh[256];
  int t = threadIdx.x;
  int v = bucketCnt[t];
  sh[t] = v; __syncthreads();
  for (int o = 1; o < 256; o <<= 1) {
    int x = (t >= o) ? sh[t - o] : 0;
    __syncthreads();
    sh[t] += x;
    __syncthreads();
  }
  int ex = sh[t] - v;
  bstart[t] = ex;
  gcur[t] = ex;
  if (t == 255) { bstart[256] = E; rowp[n] = E; }
}

__global__ __launch_bounds__(256) void k_part(const int* __restrict__ src,
                                              const int* __restrict__ dst, int E,
                                              int* __restrict__ gcur, int2* __restrict__ part) {
  __shared__ int bcnt[256], bbase[256], bcur[256];
  int t = threadIdx.x;
  int e0 = blockIdx.x * 4096, e1 = min(e0 + 4096, E);
  bcnt[t] = 0;
  __syncthreads();
  for (int e = e0 + t; e < e1; e += 256) atomicAdd(&bcnt[dst[e] >> 9], 1);
  __syncthreads();
  bbase[t] = bcnt[t] ? atomicAdd(&gcur[t], bcnt[t]) : 0;
  bcur[t] = 0;
  __syncthreads();
  for (int e = e0 + t; e < e1; e += 256) {
    int d = dst[e], s = src[e];
    int b = d >> 9;
    int off = atomicAdd(&bcur[b], 1);
    part[bbase[b] + off] = make_int2(s, d);
  }
}

__global__ __launch_bounds__(256) void k_build(const int2* __restrict__ part,
                                               const int* __restrict__ bstart,
                                               int* __restrict__ rowp, int* __restrict__ col,
                                               float* __restrict__ dinv, int n) {
  __shared__ int cnt[512], off[512], tmp[256];
  int b = blockIdx.x;
  int lo = b << 9;
  if (lo >= n) return;
  int t = threadIdx.x;
  int s0 = bstart[b], s1 = bstart[b + 1];
  cnt[t] = 0; cnt[t + 256] = 0;
  __syncthreads();
  for (int e = s0 + t; e < s1; e += 256) atomicAdd(&cnt[part[e].y - lo], 1);
  __syncthreads();
  int a0 = cnt[2 * t], a1 = cnt[2 * t + 1];
  int ps = a0 + a1;
  tmp[t] = ps; __syncthreads();
  for (int o = 1; o < 256; o <<= 1) {
    int x = (t >= o) ? tmp[t - o] : 0;
    __syncthreads();
    tmp[t] += x;
    __syncthreads();
  }
  int ex = tmp[t] - ps;
  off[2 * t] = ex;
  off[2 * t + 1] = ex + a0;
  __syncthreads();
  for (int i = t; i < 512; i += 256) {
    int node = lo + i;
    if (node < n) {
      rowp[node] = s0 + off[i];
      dinv[node] = rsqrtf((float)(cnt[i] + 1));
    }
  }
  __syncthreads();
  for (int e = s0 + t; e < s1; e += 256) {
    int2 pr = part[e];
    int p = atomicAdd(&off[pr.y - lo], 1);
    col[s0 + p] = pr.x;
  }
}

// ---------------- f32 -> bf16 convert ----------------

__global__ void k_tobf(const float* __restrict__ in, unsigned short* __restrict__ out, int n8) {
  int i = blockIdx.x * blockDim.x + threadIdx.x;
  if (i < n8) {
    const float4* i4 = (const float4*)in;
    float4 a = i4[2 * i], b = i4[2 * i + 1];
    ushort8v r;
    r[0] = f2bf(a.x); r[1] = f2bf(a.y); r[2] = f2bf(a.z); r[3] = f2bf(a.w);
    r[4] = f2bf(b.x); r[5] = f2bf(b.y); r[6] = f2bf(b.z); r[7] = f2bf(b.w);
    ((ushort8v*)out)[i] = r;
  }
}

// ---- W prep: bf16, transposed to [n][k], chunk-swizzled LDS image ----

__global__ void k_wprep(const float* __restrict__ W, unsigned short* __restrict__ out,
                        int K, int DOUT) {
  int id = blockIdx.x * blockDim.x + threadIdx.x;   // id = k*DOUT + n
  if (id < K * DOUT) {
    int k = id / DOUT, n = id % DOUT;
    int CM = (K >> 3) - 1;
    out[n * K + (((k >> 3) + n) & CM) * 8 + (k & 7)] = f2bf(W[id]);
  }
}

// -------- GCN aggregate (bf16 in): out[d] = dinv[d]*(sum dinv[s]*x[s] + dinv[d]*x[d]) --------

template<int D, bool OUTBF, bool ADD_BIAS>
__global__ __launch_bounds__(256) void k_agg(
    const unsigned short* __restrict__ xin, void* __restrict__ xout,
    const int* __restrict__ rowp, const int* __restrict__ col,
    const float* __restrict__ dinv, const float* __restrict__ bias, int n) {
  constexpr int G = D / 8;
  constexpr int NPB = 256 / G;
  int node = blockIdx.x * NPB + threadIdx.x / G;
  int g = threadIdx.x % G;
  if (node >= n) return;
  const ushort8v* x8 = (const ushort8v*)xin;
  float di = dinv[node];
  float acc[8];
  {
    ushort8v xs = x8[(size_t)node * G + g];
#pragma unroll
    for (int j = 0; j < 8; ++j) acc[j] = di * bf2f(xs[j]);
  }
  int e = rowp[node], e1 = rowp[node + 1];
  for (; e + 4 <= e1; e += 4) {
    int s0 = col[e], s1 = col[e + 1], s2 = col[e + 2], s3 = col[e + 3];
    float w0 = dinv[s0], w1 = dinv[s1], w2 = dinv[s2], w3 = dinv[s3];
    ushort8v v0 = x8[(size_t)s0 * G + g];
    ushort8v v1 = x8[(size_t)s1 * G + g];
    ushort8v v2 = x8[(size_t)s2 * G + g];
    ushort8v v3 = x8[(size_t)s3 * G + g];
#pragma unroll
    for (int j = 0; j < 8; ++j) {
      acc[j] += w0 * bf2f(v0[j]);
      acc[j] += w1 * bf2f(v1[j]);
      acc[j] += w2 * bf2f(v2[j]);
      acc[j] += w3 * bf2f(v3[j]);
    }
  }
  for (; e < e1; ++e) {
    int s = col[e];
    float w = dinv[s];
    ushort8v v = x8[(size_t)s * G + g];
#pragma unroll
    for (int j = 0; j < 8; ++j) acc[j] += w * bf2f(v[j]);
  }
  float r[8];
#pragma unroll
  for (int j = 0; j < 8; ++j) {
    r[j] = di * acc[j];
    if (ADD_BIAS) r[j] += bias[g * 8 + j];
  }
  if (OUTBF) {
    ushort8v o;
#pragma unroll
    for (int j = 0; j < 8; ++j) o[j] = f2bf(r[j]);
    ((ushort8v*)xout)[(size_t)node * G + g] = o;
  } else {
    float* op = (float*)xout + (size_t)node * D + g * 8;
    *(float4*)(op + 0) = make_float4(r[0], r[1], r[2], r[3]);
    *(float4*)(op + 4) = make_float4(r[4], r[5], r[6], r[7]);
  }
}

// ---------------- MFMA GEMM: C[n x DOUT](bf16) = A[n x K](bf16) @ W + bias, opt relu ----
// 128-row tile, full DOUT per block, 4 waves. LDS chunk-swizzled, conflict-free.

template<int K, int DOUT, bool RELU>
__global__ __launch_bounds__(256) void k_mgemm(
    const unsigned short* __restrict__ A, const unsigned short* __restrict__ Wp,
    const float* __restrict__ bias, unsigned short* __restrict__ C, int n) {
  constexpr int CPR = K / 8;        // ushort8 chunks per row
  constexpr int CM = CPR - 1;
  constexpr int NT = DOUT / 16;     // col tiles
  __shared__ unsigned short As[128 * K];
  __shared__ unsigned short Ws[DOUT * K];
  int t = threadIdx.x;
  int blockM = blockIdx.x * 128;

  // stage A tile (swizzled)
#pragma unroll
  for (int id = t; id < 128 * CPR; id += 256) {
    int r = id / CPR, c = id % CPR;
    int grow = blockM + r;
    ushort8v v = {0, 0, 0, 0, 0, 0, 0, 0};
    if (grow < n) v = ((const ushort8v*)A)[(size_t)grow * CPR + c];
    *(ushort8v*)&As[r * K + ((c + r) & CM) * 8] = v;
  }
  // stage W image (already in final layout)
#pragma unroll
  for (int id = t; id < DOUT * CPR; id += 256) {
    ((ushort8v*)Ws)[id] = ((const ushort8v*)Wp)[id];
  }
  __syncthreads();

  int lane = t & 63, wave = t >> 6;
  int m15 = lane & 15, quad = lane >> 4;
  f32x4 acc[2][NT];
#pragma unroll
  for (int i = 0; i < 2; ++i)
#pragma unroll
    for (int j = 0; j < NT; ++j) acc[i][j] = (f32x4){0.f, 0.f, 0.f, 0.f};

  int i0 = wave * 32 + m15;
  int i1 = i0 + 16;
#pragma unroll
  for (int kc = 0; kc < K; kc += 32) {
    int c0 = (kc >> 3) + quad;
    short8v a0 = *(const short8v*)&As[i0 * K + ((c0 + i0) & CM) * 8];
    short8v a1 = *(const short8v*)&As[i1 * K + ((c0 + i1) & CM) * 8];
    short8v b[NT];
#pragma unroll
    for (int nt = 0; nt < NT; ++nt) {
      int nn = nt * 16 + m15;
      b[nt] = *(const short8v*)&Ws[nn * K + ((c0 + nn) & CM) * 8];
    }
#pragma unroll
    for (int nt = 0; nt < NT; ++nt) {
      acc[0][nt] = __builtin_amdgcn_mfma_f32_16x16x32_bf16(a0, b[nt], acc[0][nt], 0, 0, 0);
      acc[1][nt] = __builtin_amdgcn_mfma_f32_16x16x32_bf16(a1, b[nt], acc[1][nt], 0, 0, 0);
    }
  }

  // epilogue: bias + relu + bf16 store.  C/D: row = quad*4+reg, col = lane&15.
#pragma unroll
  for (int rt = 0; rt < 2; ++rt) {
    int rbase = blockM + wave * 32 + rt * 16 + quad * 4;
#pragma unroll
    for (int nt = 0; nt < NT; ++nt) {
      int colg = nt * 16 + m15;
      float bv = bias ? bias[colg] : 0.f;
#pragma unroll
      for (int r = 0; r < 4; ++r) {
        int row = rbase + r;
        if (row < n) {
          float v = acc[rt][nt][r] + bv;
          if (RELU) v = fmaxf(v, 0.f);
          C[(size_t)row * DOUT + colg] = f2bf(v);
        }
      }
    }
  }
}

// ---------------- attention pooling (f32 in) ----------------

__global__ void k_colmean(const float* __restrict__ x, int n, double* __restrict__ gcsum) {
  __shared__ double sd[256];
  int t = threadIdx.x;
  int f = t & 63, rg = t >> 6;
  double acc = 0.0;
  for (int r = blockIdx.x * 4 + rg; r < n; r += gridDim.x * 4)
    acc += (double)x[(size_t)r * 64 + f];
  sd[t] = acc; __syncthreads();
  if (t < 64) {
    double tot = sd[t] + sd[t + 64] + sd[t + 128] + sd[t + 192];
    atomicAdd(&gcsum[t], tot);
  }
}

__global__ void k_gc(const double* __restrict__ gcsum, const float* __restrict__ Wa,
                     int n, float* __restrict__ gc) {
  __shared__ float m[64];
  int t = threadIdx.x;
  m[t] = (float)(gcsum[t] / (double)n);
  __syncthreads();
  float s = 0.f;
  for (int d = 0; d < 64; ++d) s += m[d] * Wa[d * 64 + t];
  gc[t] = tanhf(s);
}

__global__ void k_hsum(const float* __restrict__ x, const float* __restrict__ gc,
                       int n, double* __restrict__ hsum) {
  __shared__ double sd[256][4];
  int t = threadIdx.x;
  int g = t & 15, sub = t >> 4;
  float4 gcv = ((const float4*)gc)[g];
  double a0 = 0, a1 = 0, a2 = 0, a3 = 0;
  for (int node = blockIdx.x * 16 + sub; node < n; node += gridDim.x * 16) {
    float4 xv = ((const float4*)x)[(size_t)node * 16 + g];
    float p = xv.x * gcv.x + xv.y * gcv.y + xv.z * gcv.z + xv.w * gcv.w;
    p += __shfl_xor(p, 1);
    p += __shfl_xor(p, 2);
    p += __shfl_xor(p, 4);
    p += __shfl_xor(p, 8);
    float att = 1.f / (1.f + expf(-p));
    a0 += (double)(att * xv.x); a1 += (double)(att * xv.y);
    a2 += (double)(att * xv.z); a3 += (double)(att * xv.w);
  }
  sd[t][0] = a0; sd[t][1] = a1; sd[t][2] = a2; sd[t][3] = a3;
  __syncthreads();
  if (t < 64) {
    int gg = t >> 2, j = t & 3;
    double tot = 0;
    for (int w = 0; w < 16; ++w) tot += sd[w * 16 + gg][j];
    atomicAdd(&hsum[t], tot);
  }
}

// ---------------- NTN + MLP ----------------

__global__ __launch_bounds__(256) void k_ntn(
    const double* __restrict__ hid, const double* __restrict__ hjd,
    const float* __restrict__ Wt, const float* __restrict__ Wm,
    const float* __restrict__ bn, float* __restrict__ z) {
  __shared__ float hi[64], hj[64], red[256];
  int b = blockIdx.x, t = threadIdx.x;
  if (t < 64) hi[t] = (float)hid[t];
  else if (t < 128) hj[t - 64] = (float)hjd[t - 64];
  __syncthreads();
  int r = t >> 2, c0 = (t & 3) * 16;
  const float* wr = Wt + ((size_t)b * 64 + r) * 64 + c0;
  float p = 0.f;
#pragma unroll
  for (int c = 0; c < 16; ++c) p += wr[c] * hj[c0 + c];
  p *= hi[r];
  if (t < 128) p += Wm[b * 128 + t] * (t < 64 ? hi[t] : hj[t - 64]);
  red[t] = p; __syncthreads();
  for (int o = 128; o > 0; o >>= 1) {
    if (t < o) red[t] += red[t + o];
    __syncthreads();
  }
  if (t == 0) z[b] = tanhf(red[0] + bn[b]);
}

__global__ void k_mlp(const float* __restrict__ z16,
                      const float* __restrict__ w0, const float* __restrict__ b0,
                      const float* __restrict__ w1, const float* __restrict__ b1,
                      const float* __restrict__ w2, const float* __restrict__ b2,
                      const float* __restrict__ w3, const float* __restrict__ b3,
                      const float* __restrict__ sw, const float* __restrict__ sb,
                      float* __restrict__ out) {
  __shared__ float z[16], u[32], v[16], w[8], q[4];
  int t = threadIdx.x;
  if (t < 16) z[t] = z16[t];
  __syncthreads();
  if (t < 32) {
    float s = b0[t];
    for (int i = 0; i < 16; ++i) s += z[i] * w0[i * 32 + t];
    u[t] = fmaxf(s, 0.f);
  }
  __syncthreads();
  if (t < 16) {
    float s = b1[t];
    for (int i = 0; i < 32; ++i) s += u[i] * w1[i * 16 + t];
    v[t] = fmaxf(s, 0.f);
  }
  __syncthreads();
  if (t < 8) {
    float s = b2[t];
    for (int i = 0; i < 16; ++i) s += v[i] * w2[i * 8 + t];
    w[t] = fmaxf(s, 0.f);
  }
  __syncthreads();
  if (t < 4) {
    float s = b3[t];
    for (int i = 0; i < 8; ++i) s += w[i] * w3[i * 4 + t];
    q[t] = fmaxf(s, 0.f);
  }
  __syncthreads();
  if (t == 0) {
    float s = sb[0];
    for (int i = 0; i < 4; ++i) s += q[i] * sw[i];
    out[0] = s;
  }
}

// ---------------- launch ----------------

extern "C" void kernel_launch(void* const* d_in, const int* in_sizes, int n_in,
                              void* d_out, int out_size, void* d_ws, size_t ws_size,
                              hipStream_t stream) {
  const float* x_i = (const float*)d_in[0];
  const int*   ei  = (const int*)d_in[1];
  const float* x_j = (const float*)d_in[2];
  const int*   ej  = (const int*)d_in[3];
  const float* cw0 = (const float*)d_in[4];  const float* cb0 = (const float*)d_in[5];
  const float* cw1 = (const float*)d_in[6];  const float* cb1 = (const float*)d_in[7];
  const float* cw2 = (const float*)d_in[8];  const float* cb2 = (const float*)d_in[9];
  const float* aw  = (const float*)d_in[10];
  const float* wt  = (const float*)d_in[11]; const float* wm  = (const float*)d_in[12];
  const float* bn  = (const float*)d_in[13];
  const float* m0w = (const float*)d_in[14]; const float* m0b = (const float*)d_in[15];
  const float* m1w = (const float*)d_in[16]; const float* m1b = (const float*)d_in[17];
  const float* m2w = (const float*)d_in[18]; const float* m2b = (const float*)d_in[19];
  const float* m3w = (const float*)d_in[20]; const float* m3b = (const float*)d_in[21];
  const float* sw  = (const float*)d_in[22]; const float* sb  = (const float*)d_in[23];

  int N = in_sizes[0] / 64;
  int E = in_sizes[1] / 2;

  char* p = (char*)d_ws;
  auto alloc = [&](size_t b) -> void* {
    void* r = (void*)p;
    p += (b + 255) & ~(size_t)255;
    return r;
  };
  int*    rowp  = (int*)alloc((size_t)(N + 1) * 4);
  int*    col   = (int*)alloc((size_t)E * 4);
  float*  dinv  = (float*)alloc((size_t)N * 4);
  int*    bucketCnt = (int*)alloc(256 * 4);
  int*    bstart    = (int*)alloc(257 * 4);
  int*    gcur      = (int*)alloc(256 * 4);
  double* gcsum = (double*)alloc(64 * 8);
  double* hsum  = (double*)alloc(128 * 8);
  float*  gc    = (float*)alloc(64 * 4);
  float*  zbuf  = (float*)alloc(16 * 4);
  unsigned short* w0p = (unsigned short*)alloc(64 * 128 * 2);
  unsigned short* w1p = (unsigned short*)alloc(128 * 128 * 2);
  unsigned short* w2p = (unsigned short*)alloc(128 * 64 * 2);
  float*  S1    = (float*)alloc((size_t)N * 128 * 4);
  float*  S2    = (float*)alloc((size_t)N * 128 * 4);

  hipMemsetAsync(hsum, 0, 128 * 8, stream);

  // weight prep (bf16 + transpose + swizzle), once per call
  k_wprep<<<CDIV(64 * 128, 256), 256, 0, stream>>>(cw0, w0p, 64, 128);
  k_wprep<<<CDIV(128 * 128, 256), 256, 0, stream>>>(cw1, w1p, 128, 128);
  k_wprep<<<CDIV(128 * 64, 256), 256, 0, stream>>>(cw2, w2p, 128, 64);

  for (int g = 0; g < 2; ++g) {
    const float* X  = g ? x_j : x_i;
    const int* src  = g ? ej : ei;
    const int* dst  = src + E;
    double* hs      = hsum + g * 64;

    // ---- CSR (bucketed, write-coalesced) ----
    int2* part = (int2*)S1;  // transient
    hipMemsetAsync(bucketCnt, 0, 256 * 4, stream);
    k_bcount<<<CDIV(E, 2048), 256, 0, stream>>>(dst, E, bucketCnt);
    k_bscan<<<1, 256, 0, stream>>>(bucketCnt, bstart, gcur, rowp, N, E);
    k_part<<<CDIV(E, 4096), 256, 0, stream>>>(src, dst, E, gcur, part);
    k_build<<<256, 256, 0, stream>>>(part, bstart, rowp, col, dinv, N);

    unsigned short* xbf = (unsigned short*)S2;
    k_tobf<<<CDIV(N * 8, 256), 256, 0, stream>>>(X, xbf, N * 8);

    unsigned short* A0 = (unsigned short*)S1;
    unsigned short* G0 = (unsigned short*)S2;
    unsigned short* A1 = (unsigned short*)S1;
    unsigned short* G1 = (unsigned short*)S2;
    unsigned short* G2 = (unsigned short*)S1;
    float* F = S2;

    // L0
    k_agg<64, true, false><<<CDIV(N, 32), 256, 0, stream>>>(xbf, A0, rowp, col, dinv, nullptr, N);
    k_mgemm<64, 128, true><<<CDIV(N, 128), 256, 0, stream>>>(A0, w0p, cb0, G0, N);
    // L1
    k_agg<128, true, false><<<CDIV(N, 16), 256, 0, stream>>>(G0, A1, rowp, col, dinv, nullptr, N);
    k_mgemm<128, 128, true><<<CDIV(N, 128), 256, 0, stream>>>(A1, w1p, cb1, G1, N);
    // L2: GEMM then aggregate(+bias)
    k_mgemm<128, 64, false><<<CDIV(N, 128), 256, 0, stream>>>(G1, w2p, nullptr, G2, N);
    k_agg<64, false, true><<<CDIV(N, 32), 256, 0, stream>>>(G2, F, rowp, col, dinv, cb2, N);

    // attention pooling
    hipMemsetAsync(gcsum, 0, 64 * 8, stream);
    k_colmean<<<512, 256, 0, stream>>>(F, N, gcsum);
    k_gc<<<1, 64, 0, stream>>>(gcsum, aw, N, gc);
    k_hsum<<<512, 256, 0, stream>>>(F, gc, N, hs);
  }

  k_ntn<<<16, 256, 0, stream>>>(hsum, hsum + 64, wt, wm, bn, zbuf);
  k_mlp<<<1, 64, 0, stream>>>(zbuf, m0w, m0b, m1w, m1b, m2w, m2b, m3w, m3b,
                              sw, sb, (float*)d_out);
}